// Round 2
// baseline (93.663 us; speedup 1.0000x reference)
//
#include <hip/hip_runtime.h>

// Problem: N = 16384, f32.
// log_prob[i] = -log( sum_j [g[j] <= g[i]] * exp(logits[j] - logits[i]) + 1e-10 )
//             = -log( exp(-logits[i]) * S_i + 1e-10 ),  S_i = sum_{g[j]<=g[i]} exp(logits[j])
// outputs (concat): log_prob [N] floats, then g [N] floats.
//
// Structure: one pass over all (i,j) pairs, 2 kernels.
//   gs_partial: grid (n/IBLK, n/JCHUNK). Each block stages one j-chunk's (g_j, e_j=exp(l_j))
//               into LDS (computed inline from logits+noise), each thread accumulates 8 i's.
//               Inner loop per j: 1 broadcast ds_read_b64 + 8x{cmp,cndmask,add} -> VALU-bound.
//   gs_finalize: sums the j-chunk partials, applies -log(s*exp(-l)+eps), writes g output.
// Deterministic (no atomics) -> bitwise-stable across graph replays.

#define EPS_LOG 1e-10f

constexpr int TPB    = 256;
constexpr int IPT    = 8;            // i-values per thread
constexpr int IBLK   = TPB * IPT;    // 2048 i per block-row
constexpr int JCHUNK = 256;          // j per block-col (LDS tile: 2 KB)

// ws layout: float partial[n_jchunks][n]  (n_jchunks = n/JCHUNK = 64 -> 4 MB for n=16384)

__global__ __launch_bounds__(TPB) void gs_partial(const float* __restrict__ logits,
                                                  const float* __restrict__ noise,
                                                  float* __restrict__ partial,
                                                  int n) {
    __shared__ float2 tile[JCHUNK];
    const int ib = blockIdx.x;           // i-block
    const int jc = blockIdx.y;           // j-chunk
    const int jbase = jc * JCHUNK;

    // stage this j-chunk into LDS, computing (g, exp(l)) inline (coalesced loads)
    for (int t = threadIdx.x; t < JCHUNK; t += TPB) {
        float l = logits[jbase + t];
        tile[t] = make_float2(l + noise[jbase + t], __expf(l));
    }

    // my 8 gumbel-perturbed logits
    const int i0 = ib * IBLK + (int)threadIdx.x;
    float gi[IPT];
    #pragma unroll
    for (int k = 0; k < IPT; ++k) {
        int i = i0 + k * TPB;
        gi[k] = logits[i] + noise[i];
    }
    __syncthreads();

    float s[IPT];
    #pragma unroll
    for (int k = 0; k < IPT; ++k) s[k] = 0.0f;

    #pragma unroll 4
    for (int j = 0; j < JCHUNK; ++j) {
        float2 t = tile[j];              // broadcast LDS read (all lanes same addr, no conflict)
        #pragma unroll
        for (int k = 0; k < IPT; ++k)
            s[k] += (t.x <= gi[k]) ? t.y : 0.0f;   // v_cmp_le + v_cndmask + v_add
    }

    #pragma unroll
    for (int k = 0; k < IPT; ++k)
        partial[(size_t)jc * n + i0 + k * TPB] = s[k];
}

__global__ __launch_bounds__(TPB) void gs_finalize(const float* __restrict__ partial,
                                                   const float* __restrict__ logits,
                                                   const float* __restrict__ noise,
                                                   float* __restrict__ out,
                                                   int n, int n_jchunks) {
    int i = blockIdx.x * TPB + threadIdx.x;
    if (i >= n) return;
    float s = 0.0f;
    for (int c = 0; c < n_jchunks; ++c)
        s += partial[(size_t)c * n + i];
    float l = logits[i];
    out[i]     = -__logf(s * __expf(-l) + EPS_LOG);  // arg >= 1 (self term) -> well-conditioned
    out[n + i] = l + noise[i];                        // g output
}

extern "C" void kernel_launch(void* const* d_in, const int* in_sizes, int n_in,
                              void* d_out, int out_size, void* d_ws, size_t ws_size,
                              hipStream_t stream) {
    const float* logits = (const float*)d_in[0];
    const float* noise  = (const float*)d_in[1];
    float* out = (float*)d_out;                 // [0,n): log_prob ; [n,2n): g
    const int n = in_sizes[0];

    float* partial = (float*)d_ws;

    const int n_iblocks = (n + IBLK - 1) / IBLK;     // 8
    const int n_jchunks = (n + JCHUNK - 1) / JCHUNK; // 64

    dim3 grid(n_iblocks, n_jchunks);
    gs_partial<<<grid, TPB, 0, stream>>>(logits, noise, partial, n);
    gs_finalize<<<(n + TPB - 1) / TPB, TPB, 0, stream>>>(partial, logits, noise, out, n, n_jchunks);
}

// Round 6
// 82.728 us; speedup vs baseline: 1.1322x; 1.1322x over previous
//
#include <hip/hip_runtime.h>

// Problem: N = 16384, f32.
// log_prob[i] = -log( sum_j [g[j] <= g[i]] * exp(logits[j] - logits[i]) + 1e-10 )
//             = -log( exp(-logits[i]) * S_i + 1e-10 ),  S_i = sum_{g[j]<=g[i]} exp(logits[j])
// outputs (concat): log_prob [N] floats, then g [N] floats.
//
// gs_partial: grid (n/2048, n/128) = 8 x 128 = 1024 blocks -> 4 blocks/CU,
//   16 waves/CU (4/SIMD). Each block stages one 128-j chunk of
//   (g_j, e_j=exp(l_j)) into LDS (1 KB), reads it back as float4
//   (2 pairs / ds_read_b128, broadcast -> conflict-free), each thread
//   accumulates 8 i-values -> 48 VALU per DS read (VALU-bound by design).
//   Unroll 8 batches 8 b128 reads per waitcnt for latency hiding.
// gs_finalize: sums the 128 chunk-partials per i in ascending chunk order,
//   applies -log(s*exp(-l)+eps), writes both outputs.
// No atomics -> deterministic across graph replays. Summation order over j
// is globally ascending within each chunk, chunks ascending in finalize.

#define EPS_LOG 1e-10f

constexpr int TPB    = 256;
constexpr int IPT    = 8;            // i-values per thread
constexpr int IBLK   = TPB * IPT;    // 2048 i per block-row
constexpr int JCHUNK = 128;          // j per block-col (LDS tile: 1 KB)

// ws layout: float partial[n_jchunks][n]  (n_jchunks = 128 -> 8 MB for n=16384)

__global__ __launch_bounds__(TPB) void gs_partial(const float* __restrict__ logits,
                                                  const float* __restrict__ noise,
                                                  float* __restrict__ partial,
                                                  int n) {
    __shared__ __align__(16) float2 tile[JCHUNK];
    const int ib = blockIdx.x;           // i-block
    const int jc = blockIdx.y;           // j-chunk
    const int jbase = jc * JCHUNK;

    // stage this j-chunk into LDS, computing (g, exp(l)) inline
    if (threadIdx.x < JCHUNK) {
        int j = jbase + (int)threadIdx.x;
        float l = logits[j];
        tile[threadIdx.x] = make_float2(l + noise[j], __expf(l));
    }

    // my 8 gumbel-perturbed logits (issued before the barrier to overlap)
    const int i0 = ib * IBLK + (int)threadIdx.x;
    float gi[IPT];
    #pragma unroll
    for (int k = 0; k < IPT; ++k) {
        int i = i0 + k * TPB;
        gi[k] = logits[i] + noise[i];
    }
    __syncthreads();

    float s[IPT];
    #pragma unroll
    for (int k = 0; k < IPT; ++k) s[k] = 0.0f;

    const float4* __restrict__ t4 = reinterpret_cast<const float4*>(tile);
    #pragma unroll 8
    for (int jj = 0; jj < JCHUNK / 2; ++jj) {
        float4 t = t4[jj];               // broadcast ds_read_b128: 2 (g,e) pairs
        #pragma unroll
        for (int k = 0; k < IPT; ++k) {
            s[k] += (t.x <= gi[k]) ? t.y : 0.0f;   // j even
            s[k] += (t.z <= gi[k]) ? t.w : 0.0f;   // j odd (ascending j order)
        }
    }

    #pragma unroll
    for (int k = 0; k < IPT; ++k)
        partial[(size_t)jc * n + i0 + k * TPB] = s[k];
}

__global__ __launch_bounds__(TPB) void gs_finalize(const float* __restrict__ partial,
                                                   const float* __restrict__ logits,
                                                   const float* __restrict__ noise,
                                                   float* __restrict__ out,
                                                   int n, int n_jchunks) {
    int i = blockIdx.x * TPB + threadIdx.x;
    if (i >= n) return;
    float s = 0.0f;
    #pragma unroll 8
    for (int c = 0; c < n_jchunks; ++c)       // ascending chunk order
        s += partial[(size_t)c * n + i];
    float l = logits[i];
    out[i]     = -__logf(s * __expf(-l) + EPS_LOG);
    out[n + i] = l + noise[i];
}

extern "C" void kernel_launch(void* const* d_in, const int* in_sizes, int n_in,
                              void* d_out, int out_size, void* d_ws, size_t ws_size,
                              hipStream_t stream) {
    const float* logits = (const float*)d_in[0];
    const float* noise  = (const float*)d_in[1];
    float* out = (float*)d_out;                 // [0,n): log_prob ; [n,2n): g
    const int n = in_sizes[0];

    float* partial = (float*)d_ws;

    const int n_iblocks = (n + IBLK - 1) / IBLK;     // 8
    const int n_jchunks = (n + JCHUNK - 1) / JCHUNK; // 128

    dim3 grid(n_iblocks, n_jchunks);
    gs_partial<<<grid, TPB, 0, stream>>>(logits, noise, partial, n);
    gs_finalize<<<(n + TPB - 1) / TPB, TPB, 0, stream>>>(partial, logits, noise, out, n, n_jchunks);
}